// Round 18
// baseline (48.817 us; speedup 1.0000x reference)
//
#include <hip/hip_runtime.h>
#include <hip/hip_bf16.h>

#define BB 1024
#define DD 256
#define NREL 42
#define AST 264   // bf16 halves/row: 528 B rows -> 16B-aligned (b128 gathers);
                  // 132 words -> row k starts at bank 4k%32: 8 groups x 4-word
                  // spans cover all 32 banks near-uniformly for random k.

typedef __attribute__((ext_vector_type(8))) short short8_t;
typedef __attribute__((ext_vector_type(4))) short short4_t;
typedef __attribute__((ext_vector_type(4))) float f32x4;
typedef __attribute__((ext_vector_type(4))) int   i32x4;
typedef __attribute__((ext_vector_type(4))) unsigned int u32x4;

__device__ __forceinline__ unsigned short bf16_of(float f) {
    // round-to-nearest-even f32 -> bf16 (inputs are finite normals)
    unsigned u = __float_as_uint(f);
    return (unsigned short)((u + 0x7FFFu + ((u >> 16) & 1u)) >> 16);
}

__device__ __forceinline__ float blo(unsigned u) { return __uint_as_float(u << 16); }
__device__ __forceinline__ float bhi(unsigned u) { return __uint_as_float(u & 0xFFFF0000u); }

// 8 bf16 terms: A halves in av, x halves in xv; f32 fma chain (exact expand)
__device__ __forceinline__ float dot8bf(u32x4 av, u32x4 xv, float acc) {
    acc = fmaf(blo(av[0]), blo(xv[0]), acc);
    acc = fmaf(bhi(av[0]), bhi(xv[0]), acc);
    acc = fmaf(blo(av[1]), blo(xv[1]), acc);
    acc = fmaf(bhi(av[1]), bhi(xv[1]), acc);
    acc = fmaf(blo(av[2]), blo(xv[2]), acc);
    acc = fmaf(bhi(av[2]), bhi(xv[2]), acc);
    acc = fmaf(blo(av[3]), blo(xv[3]), acc);
    acc = fmaf(bhi(av[3]), bhi(xv[3]), acc);
    return acc;
}

// ---------------- K0: x -> bf16 interleaved xh8 [d8][j][8] + bf16 transposed xbfT
__global__ __launch_bounds__(256) void cvt_kernel(const float* __restrict__ x,
                                                  unsigned short* __restrict__ xh8,
                                                  unsigned short* __restrict__ xbfT) {
    __shared__ float t32[64][68];
    const int bj = blockIdx.x * 64;
    const int bd = blockIdx.y * 64;
    const int tid = threadIdx.x;
    const int tr = tid >> 4;
    const int tc = tid & 15;

    #pragma unroll
    for (int rr = 0; rr < 4; ++rr) {
        const int jl = rr * 16 + tr;
        const f32x4 v = *reinterpret_cast<const f32x4*>(&x[(bj + jl) * DD + bd + tc * 4]);
        *reinterpret_cast<f32x4*>(&t32[jl][tc * 4]) = v;
    }
    __syncthreads();

    // bf16 transposed copy for the output GEMM
    #pragma unroll
    for (int rr = 0; rr < 4; ++rr) {
        const int dl = rr * 16 + tr;
        short4_t h;
        #pragma unroll
        for (int e = 0; e < 4; ++e) h[e] = (short)bf16_of(t32[tc * 4 + e][dl]);
        *reinterpret_cast<short4_t*>(&xbfT[(bd + dl) * BB + bj + tc * 4]) = h;
    }

    // bf16 interleaved: cell (jl, d8l); 512 cells over 256 threads
    #pragma unroll
    for (int c = 0; c < 2; ++c) {
        const int idx = c * 256 + tid;
        const int jl  = idx & 63;
        const int d8l = idx >> 6;           // 0..7
        short8_t hv;
        #pragma unroll
        for (int e = 0; e < 8; ++e) hv[e] = (short)bf16_of(t32[jl][d8l * 8 + e]);
        *reinterpret_cast<short8_t*>(
            &xh8[(size_t)((bd >> 3) + d8l) * (BB * 8) + (bj + jl) * 8]) = hv;
    }
}

// ---------------- K1 (fused): direct bf16 gather-dot + softmax -> normalized P --
// 1024 blocks x 256 thr (4 blocks/CU -> 16 waves/CU). Block = one i.
// A_i[k][d] = bf16(R[k][d]*x[i][d]) staged in LDS (42 rows x 264-half stride ->
// 16B-aligned rows). Each lane owns 4 j's: acc_j = sum_d A_i[q[i,j]][d]*x[j][d]
// via bf16->f32 expand + f32 fmaf (bit-identical to r17's passing arithmetic).
// CHANGE vs r17: A gather is ONE ds_read_b128 per stream per d8 (was 2x b64)
// -> 128 LDS instrs/lane (was 256), near-uniform bank spread (AST=264).
// x reads stay 16B/lane fully-coalesced from bf16-interleaved xh8.
__global__ __launch_bounds__(256) void attn_kernel(const float* __restrict__ x,
                                                   const int* __restrict__ q,
                                                   const float* __restrict__ R,
                                                   const unsigned short* __restrict__ xh8,
                                                   unsigned short* __restrict__ P) {
    __shared__ __align__(16) unsigned short Ah[NREL * AST];   // 22176 B
    __shared__ float s_attn[BB];                              // 4096 B
    __shared__ unsigned short s_qs[BB];                       // 2048 B

    const int tid  = threadIdx.x;
    const int w    = tid >> 6;       // 0..3: j-quarter
    const int lane = tid & 63;
    const int i    = blockIdx.x;

    // --- q row -> LDS (u16) ---
    {
        const int c4 = tid * 4;
        const i32x4 qa = *reinterpret_cast<const i32x4*>(&q[i * BB + c4]);
        short4_t sa;
        sa[0] = (short)qa[0]; sa[1] = (short)qa[1];
        sa[2] = (short)qa[2]; sa[3] = (short)qa[3];
        *reinterpret_cast<short4_t*>(&s_qs[c4]) = sa;
    }

    // --- stage A_i (bf16): 42 rows x 32 chunks of 8 = 1344 chunks ---
    for (int c = tid; c < NREL * 32; c += 256) {
        const int k  = c >> 5;
        const int d0 = (c & 31) * 8;
        const f32x4 r0 = *reinterpret_cast<const f32x4*>(&R[k * DD + d0]);
        const f32x4 r1 = *reinterpret_cast<const f32x4*>(&R[k * DD + d0 + 4]);
        const f32x4 x0 = *reinterpret_cast<const f32x4*>(&x[i * DD + d0]);
        const f32x4 x1 = *reinterpret_cast<const f32x4*>(&x[i * DD + d0 + 4]);
        short8_t hv;
        #pragma unroll
        for (int e = 0; e < 4; ++e) {
            hv[e]     = (short)bf16_of(r0[e] * x0[e]);
            hv[e + 4] = (short)bf16_of(r1[e] * x1[e]);
        }
        *reinterpret_cast<short8_t*>(&Ah[k * AST + d0]) = hv;   // 16B store
    }

    __syncthreads();

    // --- 4 interleaved j-streams per lane ---
    const int j0 = w * 256 + lane;
    const unsigned short* a0 = &Ah[(int)s_qs[j0]       * AST];
    const unsigned short* a1 = &Ah[(int)s_qs[j0 + 64]  * AST];
    const unsigned short* a2 = &Ah[(int)s_qs[j0 + 128] * AST];
    const unsigned short* a3 = &Ah[(int)s_qs[j0 + 192] * AST];
    const unsigned short* xp = xh8 + (size_t)j0 * 8;

    float acc0 = 0.f, acc1 = 0.f, acc2 = 0.f, acc3 = 0.f;

    #pragma unroll 2
    for (int d8 = 0; d8 < 32; ++d8) {
        const unsigned short* xb = xp + (size_t)d8 * (BB * 8);
        const u32x4 xv0 = *reinterpret_cast<const u32x4*>(xb);
        const u32x4 xv1 = *reinterpret_cast<const u32x4*>(xb + 64 * 8);
        const u32x4 xv2 = *reinterpret_cast<const u32x4*>(xb + 128 * 8);
        const u32x4 xv3 = *reinterpret_cast<const u32x4*>(xb + 192 * 8);

        const int ao = d8 * 8;
        const u32x4 av0 = *reinterpret_cast<const u32x4*>(a0 + ao);   // ds_read_b128
        const u32x4 av1 = *reinterpret_cast<const u32x4*>(a1 + ao);
        const u32x4 av2 = *reinterpret_cast<const u32x4*>(a2 + ao);
        const u32x4 av3 = *reinterpret_cast<const u32x4*>(a3 + ao);

        acc0 = dot8bf(av0, xv0, acc0);
        acc1 = dot8bf(av1, xv1, acc1);
        acc2 = dot8bf(av2, xv2, acc2);
        acc3 = dot8bf(av3, xv3, acc3);
    }

    s_attn[j0]       = acc0;
    s_attn[j0 + 64]  = acc1;
    s_attn[j0 + 128] = acc2;
    s_attn[j0 + 192] = acc3;

    __syncthreads();

    // --- softmax: full-row reduce (redundant x4), write own P quarter ---
    f32x4 v4[4];
    #pragma unroll
    for (int kk = 0; kk < 4; ++kk)
        v4[kk] = *reinterpret_cast<const f32x4*>(&s_attn[kk * 256 + lane * 4]);

    float m = -1e30f;
    #pragma unroll
    for (int kk = 0; kk < 4; ++kk)
        m = fmaxf(m, fmaxf(fmaxf(v4[kk][0], v4[kk][1]), fmaxf(v4[kk][2], v4[kk][3])));
    #pragma unroll
    for (int off = 1; off < 64; off <<= 1) m = fmaxf(m, __shfl_xor(m, off));

    float e[16];
    float ssum = 0.f;
    #pragma unroll
    for (int kk = 0; kk < 4; ++kk)
        #pragma unroll
        for (int ee = 0; ee < 4; ++ee) {
            const float t2 = __expf(v4[kk][ee] - m);
            e[kk * 4 + ee] = t2;
            ssum += t2;
        }
    #pragma unroll
    for (int off = 1; off < 64; off <<= 1) ssum += __shfl_xor(ssum, off);
    const float inv = 1.0f / ssum;

    {
        short4_t pv;
        #pragma unroll
        for (int ee = 0; ee < 4; ++ee) pv[ee] = (short)bf16_of(e[w * 4 + ee] * inv);
        *reinterpret_cast<short4_t*>(&P[i * BB + w * 256 + lane * 4]) = pv;
    }
}

// ---------------- K3a: partial out GEMM, split-K z=4 -----------------------------
__global__ __launch_bounds__(256) void out_partial(const unsigned short* __restrict__ P,
                                                   const unsigned short* __restrict__ xbfT,
                                                   float* __restrict__ part) {
    const int tid = threadIdx.x;
    const int wave = tid >> 6, lane = tid & 63;
    const int lcol = lane & 15;
    const int lk8  = (lane >> 4) * 8;
    const int i0 = blockIdx.y * 64 + wave * 16;
    const int d0 = blockIdx.x * 64;
    const int k0 = blockIdx.z * 256;

    f32x4 acc[4];
    #pragma unroll
    for (int nt = 0; nt < 4; ++nt) acc[nt] = (f32x4)0.0f;

    #pragma unroll
    for (int ks = 0; ks < 8; ++ks) {
        const short8_t a = *reinterpret_cast<const short8_t*>(
            &P[(i0 + lcol) * BB + k0 + ks * 32 + lk8]);
        #pragma unroll
        for (int nt = 0; nt < 4; ++nt) {
            const short8_t b = *reinterpret_cast<const short8_t*>(
                &xbfT[(d0 + nt * 16 + lcol) * BB + k0 + ks * 32 + lk8]);
            acc[nt] = __builtin_amdgcn_mfma_f32_16x16x32_bf16(a, b, acc[nt], 0, 0, 0);
        }
    }

    const int rbase = (lane >> 4) * 4;
    float* pz = part + (size_t)blockIdx.z * BB * DD;
    #pragma unroll
    for (int r = 0; r < 4; ++r)
        #pragma unroll
        for (int nt = 0; nt < 4; ++nt)
            pz[(i0 + rbase + r) * DD + d0 + nt * 16 + lcol] = acc[nt][r];
}

// ---------------- K3b: out = sum_z part[z] (P already normalized) ---------------
__global__ __launch_bounds__(256) void out_reduce(const float* __restrict__ part,
                                                  float* __restrict__ out) {
    const int idx = blockIdx.x * DD + threadIdx.x;
    out[idx] = (part[idx] + part[BB * DD + idx]) +
               (part[2 * BB * DD + idx] + part[3 * BB * DD + idx]);
}

// ---------------- launch ---------------------------------------------------------
extern "C" void kernel_launch(void* const* d_in, const int* in_sizes, int n_in,
                              void* d_out, int out_size, void* d_ws, size_t ws_size,
                              hipStream_t stream) {
    (void)in_sizes; (void)n_in; (void)out_size; (void)ws_size;
    const float* x = (const float*)d_in[0];
    // d_in[1] = x_mask (unused), d_in[3] = f (unused)
    const int* q = (const int*)d_in[2];
    const float* R = (const float*)d_in[4];
    float* out = (float*)d_out;

    char* ws = (char*)d_ws;
    unsigned short* xh8  = (unsigned short*)(ws);                  // 512 KB
    unsigned short* xbfT = (unsigned short*)(ws + (512u << 10));   // 512 KB
    unsigned short* P    = (unsigned short*)(ws + (1024u << 10));  // 2 MB
    float*          part = (float*)(ws + (3072u << 10));           // 4 MB (z=4)

    cvt_kernel<<<dim3(16, 4), 256, 0, stream>>>(x, xh8, xbfT);
    attn_kernel<<<dim3(BB), 256, 0, stream>>>(x, q, R, xh8, P);
    out_partial<<<dim3(4, 16, 4), 256, 0, stream>>>(P, xbfT, part);
    out_reduce<<<dim3(BB), 256, 0, stream>>>(part, out);
}

// Round 19
// 43.793 us; speedup vs baseline: 1.1147x; 1.1147x over previous
//
#include <hip/hip_runtime.h>
#include <hip/hip_bf16.h>

#define BB 1024
#define DD 256
#define NREL 42
#define AST 264   // bf16 halves/row: 528 B rows -> 16B-aligned b128 gathers;
                  // row starts spread over 8 bank groups (4k%32) -> near-uniform

typedef __attribute__((ext_vector_type(8))) short short8_t;
typedef __attribute__((ext_vector_type(4))) short short4_t;
typedef __attribute__((ext_vector_type(4))) float f32x4;
typedef __attribute__((ext_vector_type(4))) int   i32x4;
typedef __attribute__((ext_vector_type(4))) unsigned int u32x4;

__device__ __forceinline__ unsigned short bf16_of(float f) {
    // round-to-nearest-even f32 -> bf16 (inputs are finite normals)
    unsigned u = __float_as_uint(f);
    return (unsigned short)((u + 0x7FFFu + ((u >> 16) & 1u)) >> 16);
}

__device__ __forceinline__ float blo(unsigned u) { return __uint_as_float(u << 16); }
__device__ __forceinline__ float bhi(unsigned u) { return __uint_as_float(u & 0xFFFF0000u); }

// Two 8-term bf16 dots sharing one x operand: x expansion done ONCE (CSE).
__device__ __forceinline__ void dot8bf2(u32x4 aa, u32x4 ab, u32x4 xv,
                                        float& ra, float& rb) {
    #pragma unroll
    for (int e = 0; e < 4; ++e) {
        const float xl = blo(xv[e]);
        const float xh = bhi(xv[e]);
        ra = fmaf(blo(aa[e]), xl, ra);
        ra = fmaf(bhi(aa[e]), xh, ra);
        rb = fmaf(blo(ab[e]), xl, rb);
        rb = fmaf(bhi(ab[e]), xh, rb);
    }
}

// ---------------- K0: x -> bf16 interleaved xh8 [d8][j][8] + bf16 transposed xbfT
__global__ __launch_bounds__(256) void cvt_kernel(const float* __restrict__ x,
                                                  unsigned short* __restrict__ xh8,
                                                  unsigned short* __restrict__ xbfT) {
    __shared__ float t32[64][68];
    const int bj = blockIdx.x * 64;
    const int bd = blockIdx.y * 64;
    const int tid = threadIdx.x;
    const int tr = tid >> 4;
    const int tc = tid & 15;

    #pragma unroll
    for (int rr = 0; rr < 4; ++rr) {
        const int jl = rr * 16 + tr;
        const f32x4 v = *reinterpret_cast<const f32x4*>(&x[(bj + jl) * DD + bd + tc * 4]);
        *reinterpret_cast<f32x4*>(&t32[jl][tc * 4]) = v;
    }
    __syncthreads();

    // bf16 transposed copy for the output GEMM
    #pragma unroll
    for (int rr = 0; rr < 4; ++rr) {
        const int dl = rr * 16 + tr;
        short4_t h;
        #pragma unroll
        for (int e = 0; e < 4; ++e) h[e] = (short)bf16_of(t32[tc * 4 + e][dl]);
        *reinterpret_cast<short4_t*>(&xbfT[(bd + dl) * BB + bj + tc * 4]) = h;
    }

    // bf16 interleaved: cell (jl, d8l); 512 cells over 256 threads
    #pragma unroll
    for (int c = 0; c < 2; ++c) {
        const int idx = c * 256 + tid;
        const int jl  = idx & 63;
        const int d8l = idx >> 6;           // 0..7
        short8_t hv;
        #pragma unroll
        for (int e = 0; e < 8; ++e) hv[e] = (short)bf16_of(t32[jl][d8l * 8 + e]);
        *reinterpret_cast<short8_t*>(
            &xh8[(size_t)((bd >> 3) + d8l) * (BB * 8) + (bj + jl) * 8]) = hv;
    }
}

// ---------------- K1 (fused): 2-row bf16 gather-dot + softmax -> normalized P ---
// 512 blocks x 256 thr (2 blocks/CU -> 8 waves/CU). Block = rows {2b, 2b+1}.
// CHANGE vs r18: both rows' dots computed against the SAME x load -> per-CU
// x-stream traffic halves (2 MB -> 1 MB) and the x bf16-expansion is shared
// (dot8bf2). A tables for both rows staged in LDS (2 x 42 x 264 halves).
// Each lane owns 4 j-streams x 2 i's = 8 accumulators; per d8: 4 coalesced
// 16B x loads + 8 b128 LDS gathers + 4x dot8bf2. Same passing bf16-expand
// + f32 fmaf arithmetic as r17/r18.
__global__ __launch_bounds__(256) void attn_kernel(const float* __restrict__ x,
                                                   const int* __restrict__ q,
                                                   const float* __restrict__ R,
                                                   const unsigned short* __restrict__ xh8,
                                                   unsigned short* __restrict__ P) {
    __shared__ __align__(16) unsigned short Ah[2][NREL * AST];   // 44352 B
    __shared__ float s_attn[2][BB];                              // 8192 B
    __shared__ unsigned short s_qs[2][BB];                       // 4096 B

    const int tid  = threadIdx.x;
    const int w    = tid >> 6;       // 0..3: j-quarter for the dot phase
    const int lane = tid & 63;
    const int i0   = blockIdx.x * 2;

    // --- q rows -> LDS (u16): 2 rows x 1024 over 256 threads, 8 each ---
    {
        const int r  = tid >> 7;
        const int c8 = (tid & 127) * 8;
        const int qi = i0 + r;
        const i32x4 qa = *reinterpret_cast<const i32x4*>(&q[qi * BB + c8]);
        const i32x4 qb = *reinterpret_cast<const i32x4*>(&q[qi * BB + c8 + 4]);
        short4_t sa, sb;
        sa[0] = (short)qa[0]; sa[1] = (short)qa[1]; sa[2] = (short)qa[2]; sa[3] = (short)qa[3];
        sb[0] = (short)qb[0]; sb[1] = (short)qb[1]; sb[2] = (short)qb[2]; sb[3] = (short)qb[3];
        *reinterpret_cast<short4_t*>(&s_qs[r][c8])     = sa;
        *reinterpret_cast<short4_t*>(&s_qs[r][c8 + 4]) = sb;
    }

    // --- stage A for both rows (bf16): 2 x 42 x 32 chunks of 8 ---
    #pragma unroll
    for (int i2 = 0; i2 < 2; ++i2) {
        const int i = i0 + i2;
        for (int c = tid; c < NREL * 32; c += 256) {
            const int k  = c >> 5;
            const int d0 = (c & 31) * 8;
            const f32x4 r0 = *reinterpret_cast<const f32x4*>(&R[k * DD + d0]);
            const f32x4 r1 = *reinterpret_cast<const f32x4*>(&R[k * DD + d0 + 4]);
            const f32x4 x0 = *reinterpret_cast<const f32x4*>(&x[i * DD + d0]);
            const f32x4 x1 = *reinterpret_cast<const f32x4*>(&x[i * DD + d0 + 4]);
            short8_t hv;
            #pragma unroll
            for (int e = 0; e < 4; ++e) {
                hv[e]     = (short)bf16_of(r0[e] * x0[e]);
                hv[e + 4] = (short)bf16_of(r1[e] * x1[e]);
            }
            *reinterpret_cast<short8_t*>(&Ah[i2][k * AST + d0]) = hv;   // 16B store
        }
    }

    __syncthreads();

    // --- 4 j-streams x 2 rows per lane ---
    const int j0 = w * 256 + lane;
    const unsigned short* a00 = &Ah[0][(int)s_qs[0][j0]       * AST];
    const unsigned short* a01 = &Ah[0][(int)s_qs[0][j0 + 64]  * AST];
    const unsigned short* a02 = &Ah[0][(int)s_qs[0][j0 + 128] * AST];
    const unsigned short* a03 = &Ah[0][(int)s_qs[0][j0 + 192] * AST];
    const unsigned short* a10 = &Ah[1][(int)s_qs[1][j0]       * AST];
    const unsigned short* a11 = &Ah[1][(int)s_qs[1][j0 + 64]  * AST];
    const unsigned short* a12 = &Ah[1][(int)s_qs[1][j0 + 128] * AST];
    const unsigned short* a13 = &Ah[1][(int)s_qs[1][j0 + 192] * AST];
    const unsigned short* xp = xh8 + (size_t)j0 * 8;

    float c00 = 0.f, c01 = 0.f, c02 = 0.f, c03 = 0.f;
    float c10 = 0.f, c11 = 0.f, c12 = 0.f, c13 = 0.f;

    #pragma unroll 2
    for (int d8 = 0; d8 < 32; ++d8) {
        const unsigned short* xb = xp + (size_t)d8 * (BB * 8);
        const u32x4 xv0 = *reinterpret_cast<const u32x4*>(xb);
        const u32x4 xv1 = *reinterpret_cast<const u32x4*>(xb + 64 * 8);
        const u32x4 xv2 = *reinterpret_cast<const u32x4*>(xb + 128 * 8);
        const u32x4 xv3 = *reinterpret_cast<const u32x4*>(xb + 192 * 8);

        const int ao = d8 * 8;
        const u32x4 av00 = *reinterpret_cast<const u32x4*>(a00 + ao);
        const u32x4 av01 = *reinterpret_cast<const u32x4*>(a01 + ao);
        const u32x4 av02 = *reinterpret_cast<const u32x4*>(a02 + ao);
        const u32x4 av03 = *reinterpret_cast<const u32x4*>(a03 + ao);
        const u32x4 av10 = *reinterpret_cast<const u32x4*>(a10 + ao);
        const u32x4 av11 = *reinterpret_cast<const u32x4*>(a11 + ao);
        const u32x4 av12 = *reinterpret_cast<const u32x4*>(a12 + ao);
        const u32x4 av13 = *reinterpret_cast<const u32x4*>(a13 + ao);

        dot8bf2(av00, av10, xv0, c00, c10);
        dot8bf2(av01, av11, xv1, c01, c11);
        dot8bf2(av02, av12, xv2, c02, c12);
        dot8bf2(av03, av13, xv3, c03, c13);
    }

    s_attn[0][j0]       = c00;  s_attn[1][j0]       = c10;
    s_attn[0][j0 + 64]  = c01;  s_attn[1][j0 + 64]  = c11;
    s_attn[0][j0 + 128] = c02;  s_attn[1][j0 + 128] = c12;
    s_attn[0][j0 + 192] = c03;  s_attn[1][j0 + 192] = c13;

    __syncthreads();

    // --- softmax: wave w reduces row (w&1) fully, writes half (w>>1) of P ---
    const int p2 = w & 1;
    const int jh = w >> 1;
    const int i  = i0 + p2;

    f32x4 v4[4];
    #pragma unroll
    for (int kk = 0; kk < 4; ++kk)
        v4[kk] = *reinterpret_cast<const f32x4*>(&s_attn[p2][kk * 256 + lane * 4]);

    float m = -1e30f;
    #pragma unroll
    for (int kk = 0; kk < 4; ++kk)
        m = fmaxf(m, fmaxf(fmaxf(v4[kk][0], v4[kk][1]), fmaxf(v4[kk][2], v4[kk][3])));
    #pragma unroll
    for (int off = 1; off < 64; off <<= 1) m = fmaxf(m, __shfl_xor(m, off));

    float e[16];
    float ssum = 0.f;
    #pragma unroll
    for (int kk = 0; kk < 4; ++kk)
        #pragma unroll
        for (int ee = 0; ee < 4; ++ee) {
            const float t2 = __expf(v4[kk][ee] - m);
            e[kk * 4 + ee] = t2;
            ssum += t2;
        }
    #pragma unroll
    for (int off = 1; off < 64; off <<= 1) ssum += __shfl_xor(ssum, off);
    const float inv = 1.0f / ssum;

    #pragma unroll
    for (int kk2 = 0; kk2 < 2; ++kk2) {
        const int kk = jh * 2 + kk2;
        short4_t pv;
        #pragma unroll
        for (int ee = 0; ee < 4; ++ee) pv[ee] = (short)bf16_of(e[kk * 4 + ee] * inv);
        *reinterpret_cast<short4_t*>(&P[i * BB + kk * 256 + lane * 4]) = pv;
    }
}

// ---------------- K3a: partial out GEMM, split-K z=4 -----------------------------
__global__ __launch_bounds__(256) void out_partial(const unsigned short* __restrict__ P,
                                                   const unsigned short* __restrict__ xbfT,
                                                   float* __restrict__ part) {
    const int tid = threadIdx.x;
    const int wave = tid >> 6, lane = tid & 63;
    const int lcol = lane & 15;
    const int lk8  = (lane >> 4) * 8;
    const int i0 = blockIdx.y * 64 + wave * 16;
    const int d0 = blockIdx.x * 64;
    const int k0 = blockIdx.z * 256;

    f32x4 acc[4];
    #pragma unroll
    for (int nt = 0; nt < 4; ++nt) acc[nt] = (f32x4)0.0f;

    #pragma unroll
    for (int ks = 0; ks < 8; ++ks) {
        const short8_t a = *reinterpret_cast<const short8_t*>(
            &P[(i0 + lcol) * BB + k0 + ks * 32 + lk8]);
        #pragma unroll
        for (int nt = 0; nt < 4; ++nt) {
            const short8_t b = *reinterpret_cast<const short8_t*>(
                &xbfT[(d0 + nt * 16 + lcol) * BB + k0 + ks * 32 + lk8]);
            acc[nt] = __builtin_amdgcn_mfma_f32_16x16x32_bf16(a, b, acc[nt], 0, 0, 0);
        }
    }

    const int rbase = (lane >> 4) * 4;
    float* pz = part + (size_t)blockIdx.z * BB * DD;
    #pragma unroll
    for (int r = 0; r < 4; ++r)
        #pragma unroll
        for (int nt = 0; nt < 4; ++nt)
            pz[(i0 + rbase + r) * DD + d0 + nt * 16 + lcol] = acc[nt][r];
}

// ---------------- K3b: out = sum_z part[z] (P already normalized) ---------------
__global__ __launch_bounds__(256) void out_reduce(const float* __restrict__ part,
                                                  float* __restrict__ out) {
    const int idx = blockIdx.x * DD + threadIdx.x;
    out[idx] = (part[idx] + part[BB * DD + idx]) +
               (part[2 * BB * DD + idx] + part[3 * BB * DD + idx]);
}

// ---------------- launch ---------------------------------------------------------
extern "C" void kernel_launch(void* const* d_in, const int* in_sizes, int n_in,
                              void* d_out, int out_size, void* d_ws, size_t ws_size,
                              hipStream_t stream) {
    (void)in_sizes; (void)n_in; (void)out_size; (void)ws_size;
    const float* x = (const float*)d_in[0];
    // d_in[1] = x_mask (unused), d_in[3] = f (unused)
    const int* q = (const int*)d_in[2];
    const float* R = (const float*)d_in[4];
    float* out = (float*)d_out;

    char* ws = (char*)d_ws;
    unsigned short* xh8  = (unsigned short*)(ws);                  // 512 KB
    unsigned short* xbfT = (unsigned short*)(ws + (512u << 10));   // 512 KB
    unsigned short* P    = (unsigned short*)(ws + (1024u << 10));  // 2 MB
    float*          part = (float*)(ws + (3072u << 10));           // 4 MB (z=4)

    cvt_kernel<<<dim3(16, 4), 256, 0, stream>>>(x, xh8, xbfT);
    attn_kernel<<<dim3(512), 256, 0, stream>>>(x, q, R, xh8, P);
    out_partial<<<dim3(4, 16, 4), 256, 0, stream>>>(P, xbfT, part);
    out_reduce<<<dim3(BB), 256, 0, stream>>>(part, out);
}

// Round 20
// 42.745 us; speedup vs baseline: 1.1420x; 1.0245x over previous
//
#include <hip/hip_runtime.h>
#include <hip/hip_bf16.h>

#define BB 1024
#define DD 256
#define NREL 42
#define AST 264   // bf16 halves/row: 528 B rows -> 16B-aligned b128 gathers;
                  // row starts spread over 8 bank groups (4k%32) -> near-uniform

typedef __attribute__((ext_vector_type(8))) short short8_t;
typedef __attribute__((ext_vector_type(4))) short short4_t;
typedef __attribute__((ext_vector_type(4))) float f32x4;
typedef __attribute__((ext_vector_type(4))) int   i32x4;
typedef __attribute__((ext_vector_type(4))) unsigned int u32x4;

__device__ __forceinline__ unsigned short bf16_of(float f) {
    // round-to-nearest-even f32 -> bf16 (inputs are finite normals)
    unsigned u = __float_as_uint(f);
    return (unsigned short)((u + 0x7FFFu + ((u >> 16) & 1u)) >> 16);
}

__device__ __forceinline__ float blo(unsigned u) { return __uint_as_float(u << 16); }
__device__ __forceinline__ float bhi(unsigned u) { return __uint_as_float(u & 0xFFFF0000u); }

// Four 8-term bf16 dots sharing ONE x operand: x expansion done once.
__device__ __forceinline__ void dot8bf4(u32x4 a0, u32x4 a1, u32x4 a2, u32x4 a3,
                                        u32x4 xv,
                                        float& r0, float& r1, float& r2, float& r3) {
    #pragma unroll
    for (int e = 0; e < 4; ++e) {
        const float xl = blo(xv[e]);
        const float xh = bhi(xv[e]);
        r0 = fmaf(blo(a0[e]), xl, r0);  r0 = fmaf(bhi(a0[e]), xh, r0);
        r1 = fmaf(blo(a1[e]), xl, r1);  r1 = fmaf(bhi(a1[e]), xh, r1);
        r2 = fmaf(blo(a2[e]), xl, r2);  r2 = fmaf(bhi(a2[e]), xh, r2);
        r3 = fmaf(blo(a3[e]), xl, r3);  r3 = fmaf(bhi(a3[e]), xh, r3);
    }
}

// ---------------- K0: x -> bf16 interleaved xh8 [d8][j][8] + bf16 transposed xbfT
__global__ __launch_bounds__(256) void cvt_kernel(const float* __restrict__ x,
                                                  unsigned short* __restrict__ xh8,
                                                  unsigned short* __restrict__ xbfT) {
    __shared__ float t32[64][68];
    const int bj = blockIdx.x * 64;
    const int bd = blockIdx.y * 64;
    const int tid = threadIdx.x;
    const int tr = tid >> 4;
    const int tc = tid & 15;

    #pragma unroll
    for (int rr = 0; rr < 4; ++rr) {
        const int jl = rr * 16 + tr;
        const f32x4 v = *reinterpret_cast<const f32x4*>(&x[(bj + jl) * DD + bd + tc * 4]);
        *reinterpret_cast<f32x4*>(&t32[jl][tc * 4]) = v;
    }
    __syncthreads();

    // bf16 transposed copy for the output GEMM
    #pragma unroll
    for (int rr = 0; rr < 4; ++rr) {
        const int dl = rr * 16 + tr;
        short4_t h;
        #pragma unroll
        for (int e = 0; e < 4; ++e) h[e] = (short)bf16_of(t32[tc * 4 + e][dl]);
        *reinterpret_cast<short4_t*>(&xbfT[(bd + dl) * BB + bj + tc * 4]) = h;
    }

    // bf16 interleaved: cell (jl, d8l); 512 cells over 256 threads
    #pragma unroll
    for (int c = 0; c < 2; ++c) {
        const int idx = c * 256 + tid;
        const int jl  = idx & 63;
        const int d8l = idx >> 6;           // 0..7
        short8_t hv;
        #pragma unroll
        for (int e = 0; e < 8; ++e) hv[e] = (short)bf16_of(t32[jl][d8l * 8 + e]);
        *reinterpret_cast<short8_t*>(
            &xh8[(size_t)((bd >> 3) + d8l) * (BB * 8) + (bj + jl) * 8]) = hv;
    }
}

// ---------------- K1 (fused): 4-row bf16 gather-dot + softmax -> normalized P ---
// 256 blocks x 512 thr (1 block/CU, 8 waves/CU). Block = rows {4b..4b+3}.
// CHANGE vs r19 (2-row, 43.8us): 4 rows share each x load -> per-CU x-stream
// 1 MB -> 512 KB, and the x bf16-expansion is amortized over 4 dot chains
// (dot8bf4). A tables for all 4 rows in LDS (4 x 42 x 264 halves = 88.7 KB;
// total LDS 113 KB, 1 block/CU). Each lane owns 2 j-streams x 4 rows = 8
// accumulators; per (stream,d8): 1 coalesced 16B x load + 4 b128 A-gathers +
// dot8bf4. Arithmetic bit-identical to r17-r19 (bf16 expand + f32 fmaf).
// Only 2 block-wide barriers total (post-staging, pre-softmax).
__global__ __launch_bounds__(512) void attn_kernel(const float* __restrict__ x,
                                                   const int* __restrict__ q,
                                                   const float* __restrict__ R,
                                                   const unsigned short* __restrict__ xh8,
                                                   unsigned short* __restrict__ P) {
    __shared__ __align__(16) unsigned short Ah[4][NREL * AST];   // 88704 B
    __shared__ float s_attn[4][BB];                              // 16384 B
    __shared__ unsigned short s_qs[4][BB];                       // 8192 B

    const int tid  = threadIdx.x;
    const int w    = tid >> 6;       // 0..7
    const int lane = tid & 63;
    const int i0   = blockIdx.x * 4;

    // --- q rows -> LDS (u16): 4 rows x 1024 over 512 threads, 8 each ---
    {
        const int r  = tid >> 7;            // 0..3
        const int c8 = (tid & 127) * 8;
        const int qi = i0 + r;
        const i32x4 qa = *reinterpret_cast<const i32x4*>(&q[qi * BB + c8]);
        const i32x4 qb = *reinterpret_cast<const i32x4*>(&q[qi * BB + c8 + 4]);
        short4_t sa, sb;
        sa[0] = (short)qa[0]; sa[1] = (short)qa[1]; sa[2] = (short)qa[2]; sa[3] = (short)qa[3];
        sb[0] = (short)qb[0]; sb[1] = (short)qb[1]; sb[2] = (short)qb[2]; sb[3] = (short)qb[3];
        *reinterpret_cast<short4_t*>(&s_qs[r][c8])     = sa;
        *reinterpret_cast<short4_t*>(&s_qs[r][c8 + 4]) = sb;
    }

    // --- stage A for 4 rows (bf16): 4 x 42 x 32 chunks of 8 ---
    #pragma unroll
    for (int i2 = 0; i2 < 4; ++i2) {
        const int i = i0 + i2;
        for (int c = tid; c < NREL * 32; c += 512) {
            const int k  = c >> 5;
            const int d0 = (c & 31) * 8;
            const f32x4 r0 = *reinterpret_cast<const f32x4*>(&R[k * DD + d0]);
            const f32x4 r1 = *reinterpret_cast<const f32x4*>(&R[k * DD + d0 + 4]);
            const f32x4 x0 = *reinterpret_cast<const f32x4*>(&x[i * DD + d0]);
            const f32x4 x1 = *reinterpret_cast<const f32x4*>(&x[i * DD + d0 + 4]);
            short8_t hv;
            #pragma unroll
            for (int e = 0; e < 4; ++e) {
                hv[e]     = (short)bf16_of(r0[e] * x0[e]);
                hv[e + 4] = (short)bf16_of(r1[e] * x1[e]);
            }
            *reinterpret_cast<short8_t*>(&Ah[i2][k * AST + d0]) = hv;   // 16B store
        }
    }

    __syncthreads();

    // --- 2 j-streams x 4 rows per lane ---
    const int j0 = tid;          // stream 0
    const int j1 = tid + 512;    // stream 1
    const unsigned short* a00 = &Ah[0][(int)s_qs[0][j0] * AST];
    const unsigned short* a10 = &Ah[1][(int)s_qs[1][j0] * AST];
    const unsigned short* a20 = &Ah[2][(int)s_qs[2][j0] * AST];
    const unsigned short* a30 = &Ah[3][(int)s_qs[3][j0] * AST];
    const unsigned short* a01 = &Ah[0][(int)s_qs[0][j1] * AST];
    const unsigned short* a11 = &Ah[1][(int)s_qs[1][j1] * AST];
    const unsigned short* a21 = &Ah[2][(int)s_qs[2][j1] * AST];
    const unsigned short* a31 = &Ah[3][(int)s_qs[3][j1] * AST];
    const unsigned short* xp0 = xh8 + (size_t)j0 * 8;
    const unsigned short* xp1 = xh8 + (size_t)j1 * 8;

    float c00 = 0.f, c10 = 0.f, c20 = 0.f, c30 = 0.f;   // stream 0, rows 0..3
    float c01 = 0.f, c11 = 0.f, c21 = 0.f, c31 = 0.f;   // stream 1, rows 0..3

    #pragma unroll 2
    for (int d8 = 0; d8 < 32; ++d8) {
        const size_t xo = (size_t)d8 * (BB * 8);
        const u32x4 xv0 = *reinterpret_cast<const u32x4*>(xp0 + xo);
        const u32x4 xv1 = *reinterpret_cast<const u32x4*>(xp1 + xo);

        const int ao = d8 * 8;
        const u32x4 av00 = *reinterpret_cast<const u32x4*>(a00 + ao);
        const u32x4 av10 = *reinterpret_cast<const u32x4*>(a10 + ao);
        const u32x4 av20 = *reinterpret_cast<const u32x4*>(a20 + ao);
        const u32x4 av30 = *reinterpret_cast<const u32x4*>(a30 + ao);
        const u32x4 av01 = *reinterpret_cast<const u32x4*>(a01 + ao);
        const u32x4 av11 = *reinterpret_cast<const u32x4*>(a11 + ao);
        const u32x4 av21 = *reinterpret_cast<const u32x4*>(a21 + ao);
        const u32x4 av31 = *reinterpret_cast<const u32x4*>(a31 + ao);

        dot8bf4(av00, av10, av20, av30, xv0, c00, c10, c20, c30);
        dot8bf4(av01, av11, av21, av31, xv1, c01, c11, c21, c31);
    }

    s_attn[0][j0] = c00;  s_attn[1][j0] = c10;  s_attn[2][j0] = c20;  s_attn[3][j0] = c30;
    s_attn[0][j1] = c01;  s_attn[1][j1] = c11;  s_attn[2][j1] = c21;  s_attn[3][j1] = c31;

    __syncthreads();

    // --- softmax: wave w reduces row (w>>1) fully, writes half (w&1) of P ---
    const int p2 = w >> 1;       // row 0..3
    const int jh = w & 1;        // half 0/1
    const int i  = i0 + p2;

    f32x4 v4[4];
    #pragma unroll
    for (int kk = 0; kk < 4; ++kk)
        v4[kk] = *reinterpret_cast<const f32x4*>(&s_attn[p2][kk * 256 + lane * 4]);

    float m = -1e30f;
    #pragma unroll
    for (int kk = 0; kk < 4; ++kk)
        m = fmaxf(m, fmaxf(fmaxf(v4[kk][0], v4[kk][1]), fmaxf(v4[kk][2], v4[kk][3])));
    #pragma unroll
    for (int off = 1; off < 64; off <<= 1) m = fmaxf(m, __shfl_xor(m, off));

    float e[16];
    float ssum = 0.f;
    #pragma unroll
    for (int kk = 0; kk < 4; ++kk)
        #pragma unroll
        for (int ee = 0; ee < 4; ++ee) {
            const float t2 = __expf(v4[kk][ee] - m);
            e[kk * 4 + ee] = t2;
            ssum += t2;
        }
    #pragma unroll
    for (int off = 1; off < 64; off <<= 1) ssum += __shfl_xor(ssum, off);
    const float inv = 1.0f / ssum;

    #pragma unroll
    for (int kk2 = 0; kk2 < 2; ++kk2) {
        const int kk = jh * 2 + kk2;
        short4_t pv;
        #pragma unroll
        for (int ee = 0; ee < 4; ++ee) pv[ee] = (short)bf16_of(e[kk * 4 + ee] * inv);
        *reinterpret_cast<short4_t*>(&P[i * BB + kk * 256 + lane * 4]) = pv;
    }
}

// ---------------- K3a: partial out GEMM, split-K z=4 -----------------------------
__global__ __launch_bounds__(256) void out_partial(const unsigned short* __restrict__ P,
                                                   const unsigned short* __restrict__ xbfT,
                                                   float* __restrict__ part) {
    const int tid = threadIdx.x;
    const int wave = tid >> 6, lane = tid & 63;
    const int lcol = lane & 15;
    const int lk8  = (lane >> 4) * 8;
    const int i0 = blockIdx.y * 64 + wave * 16;
    const int d0 = blockIdx.x * 64;
    const int k0 = blockIdx.z * 256;

    f32x4 acc[4];
    #pragma unroll
    for (int nt = 0; nt < 4; ++nt) acc[nt] = (f32x4)0.0f;

    #pragma unroll
    for (int ks = 0; ks < 8; ++ks) {
        const short8_t a = *reinterpret_cast<const short8_t*>(
            &P[(i0 + lcol) * BB + k0 + ks * 32 + lk8]);
        #pragma unroll
        for (int nt = 0; nt < 4; ++nt) {
            const short8_t b = *reinterpret_cast<const short8_t*>(
                &xbfT[(d0 + nt * 16 + lcol) * BB + k0 + ks * 32 + lk8]);
            acc[nt] = __builtin_amdgcn_mfma_f32_16x16x32_bf16(a, b, acc[nt], 0, 0, 0);
        }
    }

    const int rbase = (lane >> 4) * 4;
    float* pz = part + (size_t)blockIdx.z * BB * DD;
    #pragma unroll
    for (int r = 0; r < 4; ++r)
        #pragma unroll
        for (int nt = 0; nt < 4; ++nt)
            pz[(i0 + rbase + r) * DD + d0 + nt * 16 + lcol] = acc[nt][r];
}

// ---------------- K3b: out = sum_z part[z] (P already normalized) ---------------
__global__ __launch_bounds__(256) void out_reduce(const float* __restrict__ part,
                                                  float* __restrict__ out) {
    const int idx = blockIdx.x * DD + threadIdx.x;
    out[idx] = (part[idx] + part[BB * DD + idx]) +
               (part[2 * BB * DD + idx] + part[3 * BB * DD + idx]);
}

// ---------------- launch ---------------------------------------------------------
extern "C" void kernel_launch(void* const* d_in, const int* in_sizes, int n_in,
                              void* d_out, int out_size, void* d_ws, size_t ws_size,
                              hipStream_t stream) {
    (void)in_sizes; (void)n_in; (void)out_size; (void)ws_size;
    const float* x = (const float*)d_in[0];
    // d_in[1] = x_mask (unused), d_in[3] = f (unused)
    const int* q = (const int*)d_in[2];
    const float* R = (const float*)d_in[4];
    float* out = (float*)d_out;

    char* ws = (char*)d_ws;
    unsigned short* xh8  = (unsigned short*)(ws);                  // 512 KB
    unsigned short* xbfT = (unsigned short*)(ws + (512u << 10));   // 512 KB
    unsigned short* P    = (unsigned short*)(ws + (1024u << 10));  // 2 MB
    float*          part = (float*)(ws + (3072u << 10));           // 4 MB (z=4)

    cvt_kernel<<<dim3(16, 4), 256, 0, stream>>>(x, xh8, xbfT);
    attn_kernel<<<dim3(256), 512, 0, stream>>>(x, q, R, xh8, P);
    out_partial<<<dim3(4, 16, 4), 256, 0, stream>>>(P, xbfT, part);
    out_reduce<<<dim3(BB), 256, 0, stream>>>(part, out);
}

// Round 21
// 40.507 us; speedup vs baseline: 1.2051x; 1.0552x over previous
//
#include <hip/hip_runtime.h>
#include <hip/hip_bf16.h>

#define BB 1024
#define DD 256
#define NREL 42
#define AST 264   // bf16 halves/row: 528 B rows -> 16B-aligned b128 gathers;
                  // row starts spread over 8 bank groups (4k%32) -> near-uniform

typedef __attribute__((ext_vector_type(8))) short short8_t;
typedef __attribute__((ext_vector_type(4))) short short4_t;
typedef __attribute__((ext_vector_type(4))) float f32x4;
typedef __attribute__((ext_vector_type(4))) int   i32x4;
typedef __attribute__((ext_vector_type(4))) unsigned int u32x4;

__device__ __forceinline__ unsigned short bf16_of(float f) {
    // round-to-nearest-even f32 -> bf16 (inputs are finite normals)
    unsigned u = __float_as_uint(f);
    return (unsigned short)((u + 0x7FFFu + ((u >> 16) & 1u)) >> 16);
}

__device__ __forceinline__ float blo(unsigned u) { return __uint_as_float(u << 16); }
__device__ __forceinline__ float bhi(unsigned u) { return __uint_as_float(u & 0xFFFF0000u); }

// Four 8-term bf16 dots sharing ONE x operand: x expansion done once.
__device__ __forceinline__ void dot8bf4(u32x4 a0, u32x4 a1, u32x4 a2, u32x4 a3,
                                        u32x4 xv,
                                        float& r0, float& r1, float& r2, float& r3) {
    #pragma unroll
    for (int e = 0; e < 4; ++e) {
        const float xl = blo(xv[e]);
        const float xh = bhi(xv[e]);
        r0 = fmaf(blo(a0[e]), xl, r0);  r0 = fmaf(bhi(a0[e]), xh, r0);
        r1 = fmaf(blo(a1[e]), xl, r1);  r1 = fmaf(bhi(a1[e]), xh, r1);
        r2 = fmaf(blo(a2[e]), xl, r2);  r2 = fmaf(bhi(a2[e]), xh, r2);
        r3 = fmaf(blo(a3[e]), xl, r3);  r3 = fmaf(bhi(a3[e]), xh, r3);
    }
}

// ---------------- K0: x -> bf16 interleaved xh8 [d8][j][8] + bf16 transposed xbfT
__global__ __launch_bounds__(256) void cvt_kernel(const float* __restrict__ x,
                                                  unsigned short* __restrict__ xh8,
                                                  unsigned short* __restrict__ xbfT) {
    __shared__ float t32[64][68];
    const int bj = blockIdx.x * 64;
    const int bd = blockIdx.y * 64;
    const int tid = threadIdx.x;
    const int tr = tid >> 4;
    const int tc = tid & 15;

    #pragma unroll
    for (int rr = 0; rr < 4; ++rr) {
        const int jl = rr * 16 + tr;
        const f32x4 v = *reinterpret_cast<const f32x4*>(&x[(bj + jl) * DD + bd + tc * 4]);
        *reinterpret_cast<f32x4*>(&t32[jl][tc * 4]) = v;
    }
    __syncthreads();

    // bf16 transposed copy for the output GEMM
    #pragma unroll
    for (int rr = 0; rr < 4; ++rr) {
        const int dl = rr * 16 + tr;
        short4_t h;
        #pragma unroll
        for (int e = 0; e < 4; ++e) h[e] = (short)bf16_of(t32[tc * 4 + e][dl]);
        *reinterpret_cast<short4_t*>(&xbfT[(bd + dl) * BB + bj + tc * 4]) = h;
    }

    // bf16 interleaved: cell (jl, d8l); 512 cells over 256 threads
    #pragma unroll
    for (int c = 0; c < 2; ++c) {
        const int idx = c * 256 + tid;
        const int jl  = idx & 63;
        const int d8l = idx >> 6;           // 0..7
        short8_t hv;
        #pragma unroll
        for (int e = 0; e < 8; ++e) hv[e] = (short)bf16_of(t32[jl][d8l * 8 + e]);
        *reinterpret_cast<short8_t*>(
            &xh8[(size_t)((bd >> 3) + d8l) * (BB * 8) + (bj + jl) * 8]) = hv;
    }
}

// ---------------- K1 (fused): 4-row bf16 gather-dot + softmax -> normalized P ---
// 256 blocks x 1024 thr (1 block/CU, 16 waves/CU = 4/SIMD). Block = rows
// {4b..4b+3}. CHANGE vs r20 (8 waves/CU, 42.7us): per-lane work halves
// (1 j-stream x 4 rows, 4 accumulators) and wave count doubles -> the ~300cy
// L2 x-load + ~120cy LDS gather latencies (the ~11us unhidden gap in r20's
// budget) are covered by 4-way wave interleave per SIMD. Per-CU traffic and
// VALU totals are IDENTICAL to r20; arithmetic bit-identical (bf16 expand +
// f32 fmaf). Only 2 block-wide barriers (post-staging, pre-softmax).
__global__ __launch_bounds__(1024) void attn_kernel(const float* __restrict__ x,
                                                    const int* __restrict__ q,
                                                    const float* __restrict__ R,
                                                    const unsigned short* __restrict__ xh8,
                                                    unsigned short* __restrict__ P) {
    __shared__ __align__(16) unsigned short Ah[4][NREL * AST];   // 88704 B
    __shared__ float s_attn[4][BB];                              // 16384 B
    __shared__ unsigned short s_qs[4][BB];                       // 8192 B

    const int tid  = threadIdx.x;
    const int w    = tid >> 6;       // 0..15
    const int lane = tid & 63;
    const int i0   = blockIdx.x * 4;

    // --- q rows -> LDS (u16): 4 rows x 1024 over 1024 threads, 4 each ---
    {
        const int r  = tid >> 8;            // 0..3
        const int c4 = (tid & 255) * 4;
        const int qi = i0 + r;
        const i32x4 qa = *reinterpret_cast<const i32x4*>(&q[qi * BB + c4]);
        short4_t sa;
        sa[0] = (short)qa[0]; sa[1] = (short)qa[1];
        sa[2] = (short)qa[2]; sa[3] = (short)qa[3];
        *reinterpret_cast<short4_t*>(&s_qs[r][c4]) = sa;
    }

    // --- stage A for 4 rows (bf16): 4 x 42 x 32 chunks of 8 ---
    #pragma unroll
    for (int i2 = 0; i2 < 4; ++i2) {
        const int i = i0 + i2;
        for (int c = tid; c < NREL * 32; c += 1024) {
            const int k  = c >> 5;
            const int d0 = (c & 31) * 8;
            const f32x4 r0 = *reinterpret_cast<const f32x4*>(&R[k * DD + d0]);
            const f32x4 r1 = *reinterpret_cast<const f32x4*>(&R[k * DD + d0 + 4]);
            const f32x4 x0 = *reinterpret_cast<const f32x4*>(&x[i * DD + d0]);
            const f32x4 x1 = *reinterpret_cast<const f32x4*>(&x[i * DD + d0 + 4]);
            short8_t hv;
            #pragma unroll
            for (int e = 0; e < 4; ++e) {
                hv[e]     = (short)bf16_of(r0[e] * x0[e]);
                hv[e + 4] = (short)bf16_of(r1[e] * x1[e]);
            }
            *reinterpret_cast<short8_t*>(&Ah[i2][k * AST + d0]) = hv;   // 16B store
        }
    }

    __syncthreads();

    // --- 1 j-stream x 4 rows per lane ---
    const int j0 = tid;          // 0..1023: this thread's column j
    const unsigned short* a0 = &Ah[0][(int)s_qs[0][j0] * AST];
    const unsigned short* a1 = &Ah[1][(int)s_qs[1][j0] * AST];
    const unsigned short* a2 = &Ah[2][(int)s_qs[2][j0] * AST];
    const unsigned short* a3 = &Ah[3][(int)s_qs[3][j0] * AST];
    const unsigned short* xp = xh8 + (size_t)j0 * 8;

    float c0 = 0.f, c1 = 0.f, c2 = 0.f, c3 = 0.f;

    #pragma unroll 2
    for (int d8 = 0; d8 < 32; ++d8) {
        const u32x4 xv = *reinterpret_cast<const u32x4*>(xp + (size_t)d8 * (BB * 8));

        const int ao = d8 * 8;
        const u32x4 av0 = *reinterpret_cast<const u32x4*>(a0 + ao);   // ds_read_b128
        const u32x4 av1 = *reinterpret_cast<const u32x4*>(a1 + ao);
        const u32x4 av2 = *reinterpret_cast<const u32x4*>(a2 + ao);
        const u32x4 av3 = *reinterpret_cast<const u32x4*>(a3 + ao);

        dot8bf4(av0, av1, av2, av3, xv, c0, c1, c2, c3);
    }

    s_attn[0][j0] = c0;
    s_attn[1][j0] = c1;
    s_attn[2][j0] = c2;
    s_attn[3][j0] = c3;

    __syncthreads();

    // --- softmax: wave w reduces row (w>>2) fully, writes quarter (w&3) of P ---
    const int p2 = w >> 2;       // row 0..3
    const int jq = w & 3;        // quarter 0..3
    const int i  = i0 + p2;

    f32x4 v4[4];
    #pragma unroll
    for (int kk = 0; kk < 4; ++kk)
        v4[kk] = *reinterpret_cast<const f32x4*>(&s_attn[p2][kk * 256 + lane * 4]);

    float m = -1e30f;
    #pragma unroll
    for (int kk = 0; kk < 4; ++kk)
        m = fmaxf(m, fmaxf(fmaxf(v4[kk][0], v4[kk][1]), fmaxf(v4[kk][2], v4[kk][3])));
    #pragma unroll
    for (int off = 1; off < 64; off <<= 1) m = fmaxf(m, __shfl_xor(m, off));

    float e[16];
    float ssum = 0.f;
    #pragma unroll
    for (int kk = 0; kk < 4; ++kk)
        #pragma unroll
        for (int ee = 0; ee < 4; ++ee) {
            const float t2 = __expf(v4[kk][ee] - m);
            e[kk * 4 + ee] = t2;
            ssum += t2;
        }
    #pragma unroll
    for (int off = 1; off < 64; off <<= 1) ssum += __shfl_xor(ssum, off);
    const float inv = 1.0f / ssum;

    {
        short4_t pv;
        #pragma unroll
        for (int ee = 0; ee < 4; ++ee) pv[ee] = (short)bf16_of(e[jq * 4 + ee] * inv);
        *reinterpret_cast<short4_t*>(&P[i * BB + jq * 256 + lane * 4]) = pv;
    }
}

// ---------------- K3a: partial out GEMM, split-K z=4 -----------------------------
__global__ __launch_bounds__(256) void out_partial(const unsigned short* __restrict__ P,
                                                   const unsigned short* __restrict__ xbfT,
                                                   float* __restrict__ part) {
    const int tid = threadIdx.x;
    const int wave = tid >> 6, lane = tid & 63;
    const int lcol = lane & 15;
    const int lk8  = (lane >> 4) * 8;
    const int i0 = blockIdx.y * 64 + wave * 16;
    const int d0 = blockIdx.x * 64;
    const int k0 = blockIdx.z * 256;

    f32x4 acc[4];
    #pragma unroll
    for (int nt = 0; nt < 4; ++nt) acc[nt] = (f32x4)0.0f;

    #pragma unroll
    for (int ks = 0; ks < 8; ++ks) {
        const short8_t a = *reinterpret_cast<const short8_t*>(
            &P[(i0 + lcol) * BB + k0 + ks * 32 + lk8]);
        #pragma unroll
        for (int nt = 0; nt < 4; ++nt) {
            const short8_t b = *reinterpret_cast<const short8_t*>(
                &xbfT[(d0 + nt * 16 + lcol) * BB + k0 + ks * 32 + lk8]);
            acc[nt] = __builtin_amdgcn_mfma_f32_16x16x32_bf16(a, b, acc[nt], 0, 0, 0);
        }
    }

    const int rbase = (lane >> 4) * 4;
    float* pz = part + (size_t)blockIdx.z * BB * DD;
    #pragma unroll
    for (int r = 0; r < 4; ++r)
        #pragma unroll
        for (int nt = 0; nt < 4; ++nt)
            pz[(i0 + rbase + r) * DD + d0 + nt * 16 + lcol] = acc[nt][r];
}

// ---------------- K3b: out = sum_z part[z] (P already normalized) ---------------
__global__ __launch_bounds__(256) void out_reduce(const float* __restrict__ part,
                                                  float* __restrict__ out) {
    const int idx = blockIdx.x * DD + threadIdx.x;
    out[idx] = (part[idx] + part[BB * DD + idx]) +
               (part[2 * BB * DD + idx] + part[3 * BB * DD + idx]);
}

// ---------------- launch ---------------------------------------------------------
extern "C" void kernel_launch(void* const* d_in, const int* in_sizes, int n_in,
                              void* d_out, int out_size, void* d_ws, size_t ws_size,
                              hipStream_t stream) {
    (void)in_sizes; (void)n_in; (void)out_size; (void)ws_size;
    const float* x = (const float*)d_in[0];
    // d_in[1] = x_mask (unused), d_in[3] = f (unused)
    const int* q = (const int*)d_in[2];
    const float* R = (const float*)d_in[4];
    float* out = (float*)d_out;

    char* ws = (char*)d_ws;
    unsigned short* xh8  = (unsigned short*)(ws);                  // 512 KB
    unsigned short* xbfT = (unsigned short*)(ws + (512u << 10));   // 512 KB
    unsigned short* P    = (unsigned short*)(ws + (1024u << 10));  // 2 MB
    float*          part = (float*)(ws + (3072u << 10));           // 4 MB (z=4)

    cvt_kernel<<<dim3(16, 4), 256, 0, stream>>>(x, xh8, xbfT);
    attn_kernel<<<dim3(256), 1024, 0, stream>>>(x, q, R, xh8, P);
    out_partial<<<dim3(4, 16, 4), 256, 0, stream>>>(P, xbfT, part);
    out_reduce<<<dim3(BB), 256, 0, stream>>>(part, out);
}